// Round 16
// baseline (130.680 us; speedup 1.0000x reference)
//
#include <hip/hip_runtime.h>

#define K_STEPS 10

typedef float f32x2 __attribute__((ext_vector_type(2)));

__device__ __forceinline__ f32x2 fma2v(f32x2 a, f32x2 b, f32x2 c) {
    return __builtin_elementwise_fma(a, b, c);   // v_pk_fma_f32 on gfx950
}

__global__ __launch_bounds__(448, 4)
void pde_fused16(const float* __restrict__ x,
                 const float* __restrict__ conv_w,
                 const float* __restrict__ conv_b,
                 const float* __restrict__ bn_s,
                 const float* __restrict__ bn_b,
                 const float* __restrict__ bn_m,
                 const float* __restrict__ bn_v,
                 float* __restrict__ out,
                 int C, int pairs)
{
    const float DTc = 0.2f, EPSc = 1e-5f;
    // f32x2 = {plane bid, plane bid+pairs}; same channel since pairs % C == 0
    __shared__ f32x2 smem[6500];
    const int tid = threadIdx.x;
    const int bid = blockIdx.x;
    const int ch  = bid % C;
    const size_t base0 = (size_t)bid * 3136;
    const size_t base1 = (size_t)(bid + pairs) * 3136;

    f32x2* xs = smem;          // [58][58] zero-padded x tile (both planes)
    f32x2* hA = smem + 3364;   // [56][56]
    f32x2* hB = smem;          // aliases xs (dead after setup)

    // ---- zero ONLY the 232-cell border ring (interior covered by staging) ----
    if (tid < 232) {
        int o;
        if      (tid < 58)  o = tid;                       // top row
        else if (tid < 116) o = 57 * 58 + (tid - 58);      // bottom row
        else if (tid < 174) o = (tid - 116) * 58;          // left col
        else                o = (tid - 174) * 58 + 57;     // right col
        xs[o] = (f32x2){0.0f, 0.0f};
    }

    // ---- coalesced global loads, both planes ----
    float xv0[7], xv1[7];
    #pragma unroll
    for (int k = 0; k < 7; ++k) xv0[k] = x[base0 + tid + k * 448];
    #pragma unroll
    for (int k = 0; k < 7; ++k) xv1[k] = x[base1 + tid + k * 448];

    // ---- per-channel uniforms (block-uniform -> SGPRs) ----
    float wj[4][9], cbj[4];
    #pragma unroll
    for (int j = 0; j < 4; ++j) {
        #pragma unroll
        for (int tt = 0; tt < 9; ++tt) wj[j][tt] = conv_w[(j * C + ch) * 9 + tt];
        cbj[j] = conv_b[j * C + ch];
    }
    float g[5], be[5];
    #pragma unroll
    for (int j = 0; j < 5; ++j) {
        float inv = bn_s[j * C + ch] * rsqrtf(bn_v[j * C + ch] + EPSc);
        g[j]  = inv;
        be[j] = bn_b[j * C + ch] - bn_m[j * C + ch] * inv;
    }

    #pragma unroll
    for (int k = 0; k < 7; ++k) {
        int idx = tid + k * 448;
        int rr = idx / 56, cc = idx - rr * 56;
        xs[(rr + 1) * 58 + (cc + 1)] = (f32x2){xv0[k], xv1[k]};
    }
    __syncthreads();

    // ---- this thread's 1x7 chunk: row r, cols c0..c0+6 (both planes) ----
    const int r  = tid >> 3;
    const int c0 = (tid & 7) * 7;

    // coefficient state (A derived per step from Xp+Xm+Yp+Ym):
    // h' = (1 - S)*h + Xm*up + Xp*dn + Ym*l + Yp*r + F,  S = Xp+Xm+Yp+Ym
    f32x2 h[7], F[7], Xp[7], Xm[7], Yp[7], Ym[7];

    // per-cell 3x3 windows (9 transient f32x2) to cap setup register liveness
    #pragma unroll
    for (int i = 0; i < 7; ++i) {
        f32x2 a0 = (f32x2){cbj[0], cbj[0]};
        f32x2 a1 = (f32x2){cbj[1], cbj[1]};
        f32x2 a2 = (f32x2){cbj[2], cbj[2]};
        f32x2 a3 = (f32x2){cbj[3], cbj[3]};
        f32x2 hv;
        #pragma unroll
        for (int dr = 0; dr < 3; ++dr)
            #pragma unroll
            for (int dc = 0; dc < 3; ++dc) {
                f32x2 xw = xs[(r + dr) * 58 + (c0 + i + dc)];
                if (dr == 1 && dc == 1) hv = xw;
                float w0 = wj[0][dr * 3 + dc], w1 = wj[1][dr * 3 + dc];
                float w2 = wj[2][dr * 3 + dc], w3 = wj[3][dr * 3 + dc];
                a0 = fma2v(xw, (f32x2){w0, w0}, a0);
                a1 = fma2v(xw, (f32x2){w1, w1}, a1);
                a2 = fma2v(xw, (f32x2){w2, w2}, a2);
                a3 = fma2v(xw, (f32x2){w3, w3}, a3);
            }
        float uux = fmaxf(fmaf(a0.x, g[0], be[0]), 0.0f);
        float uuy = fmaxf(fmaf(a0.y, g[0], be[0]), 0.0f);
        float vvx = fmaxf(fmaf(a1.x, g[1], be[1]), 0.0f);
        float vvy = fmaxf(fmaf(a1.y, g[1], be[1]), 0.0f);
        float z2x = fmaf(a2.x, g[2], be[2]), z2y = fmaf(a2.y, g[2], be[2]);
        float z3x = fmaf(a3.x, g[3], be[3]), z3y = fmaf(a3.y, g[3], be[3]);
        float Dxx = 1.0f / (1.0f + __expf(-z2x));
        float Dxy = 1.0f / (1.0f + __expf(-z2y));
        float Dyx = 1.0f / (1.0f + __expf(-z3x));
        float Dyy = 1.0f / (1.0f + __expf(-z3y));
        float Ax = DTc * Dxx, Ay = DTc * Dxy;
        float Bx = DTc * Dyx, By = DTc * Dyy;
        float Ux = 0.5f * DTc * uux, Uy = 0.5f * DTc * uuy;
        float Vx = 0.5f * DTc * vvx, Vy = 0.5f * DTc * vvy;
        h[i]  = hv;
        F[i]  = (f32x2){DTc * hv.x, DTc * hv.y};
        Xp[i] = (f32x2){Ax + Ux, Ay + Uy};
        Xm[i] = (f32x2){Ax - Ux, Ay - Uy};
        Yp[i] = (f32x2){Bx + Vx, By + Vy};
        Ym[i] = (f32x2){Bx - Vx, By - Vy};
    }

    // initial h into buffer A
    const int o_me = r * 56 + c0;
    #pragma unroll
    for (int i = 0; i < 7; ++i) hA[o_me + i] = h[i];
    __syncthreads();

    // periodic-wrap neighbor offsets (jnp.roll semantics)
    const int rm = (r == 0)  ? 55 : r - 1;
    const int rp = (r == 55) ? 0  : r + 1;
    const int o_up = rm * 56 + c0;
    const int o_dn = rp * 56 + c0;
    const int o_l  = r * 56 + ((c0 == 0)  ? 55 : c0 - 1);
    const int o_r  = r * 56 + ((c0 == 49) ? 0  : c0 + 7);

    f32x2 *cur = hA, *nxt = hB;
    #pragma unroll
    for (int s = 0; s < K_STEPS; ++s) {
        f32x2 lf = cur[o_l];
        f32x2 rg = cur[o_r];
        f32x2 nh[7];
        // SCALAR v_fma_f32 (VOP3): can source AGPR-parked coefficients
        // directly, avoiding the v_accvgpr_read tax that pk-fma pays.
        #pragma unroll
        for (int i = 0; i < 7; ++i) {
            f32x2 ui = cur[o_up + i];
            f32x2 di = cur[o_dn + i];
            float hlx = (i == 0) ? lf.x : h[i - 1].x;
            float hly = (i == 0) ? lf.y : h[i - 1].y;
            float hrx = (i == 6) ? rg.x : h[i + 1].x;
            float hry = (i == 6) ? rg.y : h[i + 1].y;
            float Sx = (Xp[i].x + Xm[i].x) + (Yp[i].x + Ym[i].x);
            float Sy = (Xp[i].y + Xm[i].y) + (Yp[i].y + Ym[i].y);
            float tx = fmaf(Sx, -h[i].x, h[i].x + F[i].x);
            float ty = fmaf(Sy, -h[i].y, h[i].y + F[i].y);
            tx = fmaf(Xm[i].x, ui.x, tx);
            ty = fmaf(Xm[i].y, ui.y, ty);
            tx = fmaf(Xp[i].x, di.x, tx);
            ty = fmaf(Xp[i].y, di.y, ty);
            tx = fmaf(Ym[i].x, hlx, tx);
            ty = fmaf(Ym[i].y, hly, ty);
            tx = fmaf(Yp[i].x, hrx, tx);
            ty = fmaf(Yp[i].y, hry, ty);
            nh[i] = (f32x2){tx, ty};
        }
        #pragma unroll
        for (int i = 0; i < 7; ++i) h[i] = nh[i];
        if (s < K_STEPS - 1) {
            #pragma unroll
            for (int i = 0; i < 7; ++i) nxt[o_me + i] = nh[i];
            __syncthreads();
            f32x2* t2 = cur; cur = nxt; nxt = t2;
        }
        // last step: final state stays in h[]; no LDS write, no barriers
    }

    // ---- final bn4 + relu, stores straight from registers ----
    #pragma unroll
    for (int i = 0; i < 7; ++i) {
        size_t o = (size_t)(r * 56 + c0 + i);
        out[base0 + o] = fmaxf(fmaf(h[i].x, g[4], be[4]), 0.0f);
        out[base1 + o] = fmaxf(fmaf(h[i].y, g[4], be[4]), 0.0f);
    }
}

extern "C" void kernel_launch(void* const* d_in, const int* in_sizes, int n_in,
                              void* d_out, int out_size, void* d_ws, size_t ws_size,
                              hipStream_t stream) {
    const float* x  = (const float*)d_in[0];
    const float* cw = (const float*)d_in[1];
    const float* cb = (const float*)d_in[2];
    const float* bs = (const float*)d_in[3];
    const float* bb = (const float*)d_in[4];
    const float* bm = (const float*)d_in[5];
    const float* bv = (const float*)d_in[6];
    float* out = (float*)d_out;

    int C = in_sizes[2] / 4;            // conv_b is [4, C]
    int planes = in_sizes[0] / 3136;    // B*C planes of 56*56
    int pairs = planes / 2;             // plane p pairs with p+pairs (same channel: pairs % C == 0)

    pde_fused16<<<pairs, 448, 0, stream>>>(x, cw, cb, bs, bb, bm, bv, out, C, pairs);
}

// Round 17
// 129.433 us; speedup vs baseline: 1.0096x; 1.0096x over previous
//
#include <hip/hip_runtime.h>

#define K_STEPS 10

typedef float f32x2 __attribute__((ext_vector_type(2)));

__device__ __forceinline__ f32x2 fma2v(f32x2 a, f32x2 b, f32x2 c) {
    return __builtin_elementwise_fma(a, b, c);   // v_pk_fma_f32 on gfx950
}

__global__ __launch_bounds__(448, 4)
void pde_fused17(const float* __restrict__ x,
                 const float* __restrict__ conv_w,
                 const float* __restrict__ conv_b,
                 const float* __restrict__ bn_s,
                 const float* __restrict__ bn_b,
                 const float* __restrict__ bn_m,
                 const float* __restrict__ bn_v,
                 float* __restrict__ out,
                 int C, int pairs)
{
    const float DTc = 0.2f, EPSc = 1e-5f;
    // f32x2 = {plane bid, plane bid+pairs}; same channel since pairs % C == 0
    __shared__ f32x2 smem[6500];
    const int tid = threadIdx.x;
    const int bid = blockIdx.x;
    const int ch  = bid % C;
    const size_t base0 = (size_t)bid * 3136;
    const size_t base1 = (size_t)(bid + pairs) * 3136;

    f32x2* xs = smem;          // [58][58] zero-padded x tile (both planes)
    f32x2* hA = smem + 3364;   // [56][56]
    f32x2* hB = smem;          // aliases xs (dead after setup)

    // ---- zero ONLY the 232-cell border ring (interior covered by staging);
    // ring cells are disjoint from the staged interior, so the single
    // post-staging barrier orders both against the setup reads ----
    if (tid < 232) {
        int o;
        if      (tid < 58)  o = tid;                       // top row
        else if (tid < 116) o = 57 * 58 + (tid - 58);      // bottom row
        else if (tid < 174) o = (tid - 116) * 58;          // left col
        else                o = (tid - 174) * 58 + 57;     // right col
        xs[o] = (f32x2){0.0f, 0.0f};
    }

    // ---- coalesced global loads, both planes ----
    float xv0[7], xv1[7];
    #pragma unroll
    for (int k = 0; k < 7; ++k) xv0[k] = x[base0 + tid + k * 448];
    #pragma unroll
    for (int k = 0; k < 7; ++k) xv1[k] = x[base1 + tid + k * 448];

    // ---- per-channel uniforms (block-uniform -> SGPRs) ----
    float wj[4][9], cbj[4];
    #pragma unroll
    for (int j = 0; j < 4; ++j) {
        #pragma unroll
        for (int tt = 0; tt < 9; ++tt) wj[j][tt] = conv_w[(j * C + ch) * 9 + tt];
        cbj[j] = conv_b[j * C + ch];
    }
    float g[5], be[5];
    #pragma unroll
    for (int j = 0; j < 5; ++j) {
        float inv = bn_s[j * C + ch] * rsqrtf(bn_v[j * C + ch] + EPSc);
        g[j]  = inv;
        be[j] = bn_b[j * C + ch] - bn_m[j * C + ch] * inv;
    }

    #pragma unroll
    for (int k = 0; k < 7; ++k) {
        int idx = tid + k * 448;
        int rr = idx / 56, cc = idx - rr * 56;
        xs[(rr + 1) * 58 + (cc + 1)] = (f32x2){xv0[k], xv1[k]};
    }
    __syncthreads();

    // ---- this thread's 1x7 chunk: row r, cols c0..c0+6 (both planes) ----
    const int r  = tid >> 3;
    const int c0 = (tid & 7) * 7;

    // coefficient state (A derived per step from Xp+Xm+Yp+Ym):
    // h' = (1 - S)*h + Xm*up + Xp*dn + Ym*l + Yp*r + F,  S = Xp+Xm+Yp+Ym
    f32x2 h[7], F[7], Xp[7], Xm[7], Yp[7], Ym[7];

    // per-cell 3x3 windows (9 transient f32x2) to cap setup register liveness
    #pragma unroll
    for (int i = 0; i < 7; ++i) {
        f32x2 a0 = (f32x2){cbj[0], cbj[0]};
        f32x2 a1 = (f32x2){cbj[1], cbj[1]};
        f32x2 a2 = (f32x2){cbj[2], cbj[2]};
        f32x2 a3 = (f32x2){cbj[3], cbj[3]};
        f32x2 hv;
        #pragma unroll
        for (int dr = 0; dr < 3; ++dr)
            #pragma unroll
            for (int dc = 0; dc < 3; ++dc) {
                f32x2 xw = xs[(r + dr) * 58 + (c0 + i + dc)];
                if (dr == 1 && dc == 1) hv = xw;
                float w0 = wj[0][dr * 3 + dc], w1 = wj[1][dr * 3 + dc];
                float w2 = wj[2][dr * 3 + dc], w3 = wj[3][dr * 3 + dc];
                a0 = fma2v(xw, (f32x2){w0, w0}, a0);
                a1 = fma2v(xw, (f32x2){w1, w1}, a1);
                a2 = fma2v(xw, (f32x2){w2, w2}, a2);
                a3 = fma2v(xw, (f32x2){w3, w3}, a3);
            }
        float uux = fmaxf(fmaf(a0.x, g[0], be[0]), 0.0f);
        float uuy = fmaxf(fmaf(a0.y, g[0], be[0]), 0.0f);
        float vvx = fmaxf(fmaf(a1.x, g[1], be[1]), 0.0f);
        float vvy = fmaxf(fmaf(a1.y, g[1], be[1]), 0.0f);
        float z2x = fmaf(a2.x, g[2], be[2]), z2y = fmaf(a2.y, g[2], be[2]);
        float z3x = fmaf(a3.x, g[3], be[3]), z3y = fmaf(a3.y, g[3], be[3]);
        float Dxx = 1.0f / (1.0f + __expf(-z2x));
        float Dxy = 1.0f / (1.0f + __expf(-z2y));
        float Dyx = 1.0f / (1.0f + __expf(-z3x));
        float Dyy = 1.0f / (1.0f + __expf(-z3y));
        float Ax = DTc * Dxx, Ay = DTc * Dxy;
        float Bx = DTc * Dyx, By = DTc * Dyy;
        float Ux = 0.5f * DTc * uux, Uy = 0.5f * DTc * uuy;
        float Vx = 0.5f * DTc * vvx, Vy = 0.5f * DTc * vvy;
        h[i]  = hv;
        F[i]  = (f32x2){DTc * hv.x, DTc * hv.y};
        Xp[i] = (f32x2){Ax + Ux, Ay + Uy};
        Xm[i] = (f32x2){Ax - Ux, Ay - Uy};
        Yp[i] = (f32x2){Bx + Vx, By + Vy};
        Ym[i] = (f32x2){Bx - Vx, By - Vy};
    }

    // initial h into buffer A
    const int o_me = r * 56 + c0;
    #pragma unroll
    for (int i = 0; i < 7; ++i) hA[o_me + i] = h[i];
    __syncthreads();

    // periodic-wrap neighbor offsets (jnp.roll semantics)
    const int rm = (r == 0)  ? 55 : r - 1;
    const int rp = (r == 55) ? 0  : r + 1;
    const int o_up = rm * 56 + c0;
    const int o_dn = rp * 56 + c0;
    const int o_l  = r * 56 + ((c0 == 0)  ? 55 : c0 - 1);
    const int o_r  = r * 56 + ((c0 == 49) ? 0  : c0 + 7);

    f32x2 *cur = hA, *nxt = hB;
    #pragma unroll
    for (int s = 0; s < K_STEPS; ++s) {
        f32x2 lf = cur[o_l];
        f32x2 rg = cur[o_r];
        f32x2 nh[7];
        #pragma unroll
        for (int i = 0; i < 7; ++i) {
            f32x2 ui = cur[o_up + i];
            f32x2 di = cur[o_dn + i];
            f32x2 hl = (i == 0) ? lf : h[i - 1];
            f32x2 hr = (i == 6) ? rg : h[i + 1];
            f32x2 S  = (Xp[i] + Xm[i]) + (Yp[i] + Ym[i]);
            f32x2 tv = fma2v(S, -h[i], h[i] + F[i]);   // neg folds into v_pk_fma
            tv = fma2v(Xm[i], ui, tv);
            tv = fma2v(Xp[i], di, tv);
            tv = fma2v(Ym[i], hl, tv);
            tv = fma2v(Yp[i], hr, tv);
            nh[i] = tv;
        }
        #pragma unroll
        for (int i = 0; i < 7; ++i) h[i] = nh[i];
        if (s < K_STEPS - 1) {
            #pragma unroll
            for (int i = 0; i < 7; ++i) nxt[o_me + i] = nh[i];
            __syncthreads();
            f32x2* t2 = cur; cur = nxt; nxt = t2;
        }
        // last step: final state stays in h[]; no LDS write, no barriers
    }

    // ---- final bn4 + relu, stores straight from registers ----
    #pragma unroll
    for (int i = 0; i < 7; ++i) {
        size_t o = (size_t)(r * 56 + c0 + i);
        out[base0 + o] = fmaxf(fmaf(h[i].x, g[4], be[4]), 0.0f);
        out[base1 + o] = fmaxf(fmaf(h[i].y, g[4], be[4]), 0.0f);
    }
}

extern "C" void kernel_launch(void* const* d_in, const int* in_sizes, int n_in,
                              void* d_out, int out_size, void* d_ws, size_t ws_size,
                              hipStream_t stream) {
    const float* x  = (const float*)d_in[0];
    const float* cw = (const float*)d_in[1];
    const float* cb = (const float*)d_in[2];
    const float* bs = (const float*)d_in[3];
    const float* bb = (const float*)d_in[4];
    const float* bm = (const float*)d_in[5];
    const float* bv = (const float*)d_in[6];
    float* out = (float*)d_out;

    int C = in_sizes[2] / 4;            // conv_b is [4, C]
    int planes = in_sizes[0] / 3136;    // B*C planes of 56*56
    int pairs = planes / 2;             // plane p pairs with p+pairs (same channel: pairs % C == 0)

    pde_fused17<<<pairs, 448, 0, stream>>>(x, cw, cb, bs, bb, bm, bv, out, C, pairs);
}